// Round 3
// baseline (378.289 us; speedup 1.0000x reference)
//
#include <hip/hip_runtime.h>
#include <stdint.h>

#define BLOCK        256
#define UNROLL       4
#define MAX_BLOCKS   4096
#define WARM_BLOCKS  2048

typedef float f32x4 __attribute__((ext_vector_type(4)));

// ---------------------------------------------------------------------------
// Warm pass: sequentially touch one dword per 128B line of tar+ct so the
// whole 160MB gather target is installed in Infinity Cache via row-hit
// (sequential) DRAM activates. Runs before maha on the same stream.
// ---------------------------------------------------------------------------
__global__ __launch_bounds__(256) void llc_warm_kernel(
    const float* __restrict__ tar, long ntar_f,
    const float* __restrict__ ct,  long nct_f)
{
    const long stride = (long)gridDim.x * 256 * 32;   // 32 floats = 128B line
    const long base   = ((long)blockIdx.x * 256 + threadIdx.x) * 32;
    float acc = 0.0f;
    for (long k = base; k < nct_f; k += stride)  acc += ct[k];
    for (long k = base; k < ntar_f; k += stride) acc += tar[k];
    asm volatile("" :: "v"(acc));   // keep the touches live (rule #17)
}

// ---------------------------------------------------------------------------
// Per-point GICP mahalanobis: maha = res^T * adj(RCR) * res / det(RCR)
// RCR = C_tar[idx] + T3 * C_src * T3^T  (3x3 symmetric SPD)
// Streams (idx/src/cs) use non-temporal loads: read-once, must not evict the
// LLC-resident gather targets (tar/ct), which use normal (caching) loads.
// ---------------------------------------------------------------------------
__device__ __forceinline__ float gicp_point(
    int i,
    const float t00, const float t01, const float t02,
    const float t10, const float t11, const float t12,
    const float t20, const float t21, const float t22,
    const float t30, const float t31, const float t32,
    const f32x4* __restrict__ src, const f32x4* __restrict__ tar,
    const f32x4* __restrict__ cs,  const f32x4* __restrict__ ct,
    const int*   __restrict__ idx)
{
    const int   j  = __builtin_nontemporal_load(&idx[i]);   // stream
    const f32x4 s  = __builtin_nontemporal_load(&src[i]);   // stream
    const f32x4 tp = tar[j];                                // LLC gather

    const size_t bj = (size_t)j * 4;
    const f32x4 d0 = ct[bj + 0];                            // LLC gather
    const f32x4 d1 = ct[bj + 1];
    const f32x4 d2 = ct[bj + 2];

    const size_t bi = (size_t)i * 4;
    const f32x4 c0 = __builtin_nontemporal_load(&cs[bi + 0]);  // stream
    const f32x4 c1 = __builtin_nontemporal_load(&cs[bi + 1]);
    const f32x4 c2 = __builtin_nontemporal_load(&cs[bi + 2]);

    const float ts0 = s.x * t00 + s.y * t10 + s.z * t20 + s.w * t30;
    const float ts1 = s.x * t01 + s.y * t11 + s.z * t21 + s.w * t31;
    const float ts2 = s.x * t02 + s.y * t12 + s.z * t22 + s.w * t32;
    const float r0 = tp.x - ts0;
    const float r1 = tp.y - ts1;
    const float r2 = tp.z - ts2;

    // U = T3 * C_src
    const float u00 = t00*c0.x + t01*c1.x + t02*c2.x;
    const float u01 = t00*c0.y + t01*c1.y + t02*c2.y;
    const float u02 = t00*c0.z + t01*c1.z + t02*c2.z;
    const float u10 = t10*c0.x + t11*c1.x + t12*c2.x;
    const float u11 = t10*c0.y + t11*c1.y + t12*c2.y;
    const float u12 = t10*c0.z + t11*c1.z + t12*c2.z;
    const float u20 = t20*c0.x + t21*c1.x + t22*c2.x;
    const float u21 = t20*c0.y + t21*c1.y + t22*c2.y;
    const float u22 = t20*c0.z + t21*c1.z + t22*c2.z;

    // tcov = U * T3^T (symmetric part)
    const float tc00 = u00*t00 + u01*t01 + u02*t02;
    const float tc01 = u00*t10 + u01*t11 + u02*t12;
    const float tc02 = u00*t20 + u01*t21 + u02*t22;
    const float tc11 = u10*t10 + u11*t11 + u12*t12;
    const float tc12 = u10*t20 + u11*t21 + u12*t22;
    const float tc22 = u20*t20 + u21*t21 + u22*t22;

    const float a = d0.x + tc00;
    const float b = d0.y + tc01;
    const float c = d0.z + tc02;
    const float d = d1.y + tc11;
    const float e = d1.z + tc12;
    const float f = d2.z + tc22;

    const float A00 = d * f - e * e;
    const float A01 = c * e - b * f;
    const float A02 = b * e - c * d;
    const float A11 = a * f - c * c;
    const float A12 = b * c - a * e;
    const float A22 = a * d - b * b;

    const float det = a * A00 + b * A01 + c * A02;

    const float num = r0 * r0 * A00 + r1 * r1 * A11 + r2 * r2 * A22
                    + 2.0f * (r0 * r1 * A01 + r0 * r2 * A02 + r1 * r2 * A12);

    return num / det;
}

__global__ __launch_bounds__(BLOCK) void gicp_maha_kernel(
    const float* __restrict__ T,
    const f32x4* __restrict__ src,
    const f32x4* __restrict__ tar,
    const f32x4* __restrict__ cs,
    const f32x4* __restrict__ ct,
    const int*   __restrict__ idx,
    float*       __restrict__ partial,
    int n)
{
    const float t00 = T[0],  t01 = T[1],  t02 = T[2];
    const float t10 = T[4],  t11 = T[5],  t12 = T[6];
    const float t20 = T[8],  t21 = T[9],  t22 = T[10];
    const float t30 = T[12], t31 = T[13], t32 = T[14];

    const int stride = gridDim.x * BLOCK;   // grid exactly tiles n/UNROLL
    const int step   = stride * UNROLL;

    float local = 0.0f;
    for (int base = blockIdx.x * BLOCK + threadIdx.x; base < n; base += step) {
        if (base + 3 * stride < n) {
            float v0 = gicp_point(base,            t00,t01,t02,t10,t11,t12,t20,t21,t22,t30,t31,t32, src,tar,cs,ct,idx);
            float v1 = gicp_point(base +   stride, t00,t01,t02,t10,t11,t12,t20,t21,t22,t30,t31,t32, src,tar,cs,ct,idx);
            float v2 = gicp_point(base + 2*stride, t00,t01,t02,t10,t11,t12,t20,t21,t22,t30,t31,t32, src,tar,cs,ct,idx);
            float v3 = gicp_point(base + 3*stride, t00,t01,t02,t10,t11,t12,t20,t21,t22,t30,t31,t32, src,tar,cs,ct,idx);
            local += (v0 + v1) + (v2 + v3);
        } else {
            #pragma unroll
            for (int k = 0; k < UNROLL; ++k) {
                int i = base + k * stride;
                const float m = (i < n) ? 1.0f : 0.0f;
                i = (i < n) ? i : (n - 1);
                local += m * gicp_point(i, t00,t01,t02,t10,t11,t12,t20,t21,t22,t30,t31,t32, src,tar,cs,ct,idx);
            }
        }
    }

    // wave-64 reduction
    for (int off = 32; off > 0; off >>= 1)
        local += __shfl_down(local, off, 64);

    __shared__ float wsum[BLOCK / 64];
    const int wave = threadIdx.x >> 6;
    if ((threadIdx.x & 63) == 0) wsum[wave] = local;
    __syncthreads();
    if (threadIdx.x == 0) {
        float s = wsum[0];
        #pragma unroll
        for (int w = 1; w < BLOCK / 64; ++w) s += wsum[w];
        partial[blockIdx.x] = s;
    }
}

__global__ __launch_bounds__(256) void gicp_finalize_kernel(
    const float* __restrict__ partial, float* __restrict__ out,
    double scale, int nblocks)
{
    double s = 0.0;
    for (int k = threadIdx.x; k < nblocks; k += 256)
        s += (double)partial[k];
    for (int off = 32; off > 0; off >>= 1)
        s += __shfl_down(s, off, 64);
    __shared__ double wsum[4];
    const int wave = threadIdx.x >> 6;
    if ((threadIdx.x & 63) == 0) wsum[wave] = s;
    __syncthreads();
    if (threadIdx.x == 0)
        out[0] = (float)((wsum[0] + wsum[1] + wsum[2] + wsum[3]) * scale);
}

extern "C" void kernel_launch(void* const* d_in, const int* in_sizes, int n_in,
                              void* d_out, int out_size, void* d_ws, size_t ws_size,
                              hipStream_t stream) {
    const float* T   = (const float*)d_in[0];
    const f32x4* src = (const f32x4*)d_in[1];
    const f32x4* tar = (const f32x4*)d_in[2];
    const f32x4* cs  = (const f32x4*)d_in[3];
    const f32x4* ct  = (const f32x4*)d_in[4];
    const int*   idx = (const int*)d_in[5];
    const int n = in_sizes[1] / 4;          // src_points is (N,4) floats

    const long ntar_f = (long)(in_sizes[2]);   // floats in tar_points
    const long nct_f  = (long)(in_sizes[4]);   // floats in covs_tar

    int nblocks = (n + BLOCK * UNROLL - 1) / (BLOCK * UNROLL);
    if (nblocks < 1) nblocks = 1;
    if (nblocks > MAX_BLOCKS) nblocks = MAX_BLOCKS;
    const int ws_cap = (int)(ws_size / sizeof(float));
    if (nblocks > ws_cap) nblocks = ws_cap;

    float* partial = (float*)d_ws;

    // 1) install tar+ct into Infinity Cache via sequential (row-hit) stream
    llc_warm_kernel<<<WARM_BLOCKS, 256, 0, stream>>>(
        (const float*)tar, ntar_f, (const float*)ct, nct_f);
    // 2) gather from LLC; streams are non-temporal so they don't evict it
    gicp_maha_kernel<<<nblocks, BLOCK, 0, stream>>>(T, src, tar, cs, ct, idx,
                                                    partial, n);
    gicp_finalize_kernel<<<1, 256, 0, stream>>>(partial, (float*)d_out,
                                                0.5 / (double)n, nblocks);
}

// Round 4
// 351.644 us; speedup vs baseline: 1.0758x; 1.0758x over previous
//
#include <hip/hip_runtime.h>
#include <stdint.h>

#define BLOCK        256
#define UNROLL       4
#define MAX_BLOCKS   4096

typedef float f32x4 __attribute__((ext_vector_type(4)));

// ---------------------------------------------------------------------------
// Per-point GICP mahalanobis: maha = res^T * adj(RCR) * res / det(RCR)
// RCR = C_tar[idx] + T3 * C_src * T3^T  (3x3 symmetric SPD)
// Streams (idx/src/cs) are read-once: non-temporal (evict-first) so the
// L2/LLC retain the gathered tar/ct lines, whose ~2.9M repeat references
// then hit on-chip instead of falling through toward HBM.
// ---------------------------------------------------------------------------
__device__ __forceinline__ float gicp_point(
    int i,
    const float t00, const float t01, const float t02,
    const float t10, const float t11, const float t12,
    const float t20, const float t21, const float t22,
    const float t30, const float t31, const float t32,
    const f32x4* __restrict__ src, const f32x4* __restrict__ tar,
    const f32x4* __restrict__ cs,  const f32x4* __restrict__ ct,
    const int*   __restrict__ idx)
{
    const int   j  = __builtin_nontemporal_load(&idx[i]);   // stream
    const f32x4 s  = __builtin_nontemporal_load(&src[i]);   // stream
    const f32x4 tp = tar[j];                                // gather (cache)

    const size_t bj = (size_t)j * 4;
    const f32x4 d0 = ct[bj + 0];                            // gather (cache)
    const f32x4 d1 = ct[bj + 1];
    const f32x4 d2 = ct[bj + 2];

    const size_t bi = (size_t)i * 4;
    const f32x4 c0 = __builtin_nontemporal_load(&cs[bi + 0]);  // stream
    const f32x4 c1 = __builtin_nontemporal_load(&cs[bi + 1]);
    const f32x4 c2 = __builtin_nontemporal_load(&cs[bi + 2]);

    const float ts0 = s.x * t00 + s.y * t10 + s.z * t20 + s.w * t30;
    const float ts1 = s.x * t01 + s.y * t11 + s.z * t21 + s.w * t31;
    const float ts2 = s.x * t02 + s.y * t12 + s.z * t22 + s.w * t32;
    const float r0 = tp.x - ts0;
    const float r1 = tp.y - ts1;
    const float r2 = tp.z - ts2;

    // U = T3 * C_src
    const float u00 = t00*c0.x + t01*c1.x + t02*c2.x;
    const float u01 = t00*c0.y + t01*c1.y + t02*c2.y;
    const float u02 = t00*c0.z + t01*c1.z + t02*c2.z;
    const float u10 = t10*c0.x + t11*c1.x + t12*c2.x;
    const float u11 = t10*c0.y + t11*c1.y + t12*c2.y;
    const float u12 = t10*c0.z + t11*c1.z + t12*c2.z;
    const float u20 = t20*c0.x + t21*c1.x + t22*c2.x;
    const float u21 = t20*c0.y + t21*c1.y + t22*c2.y;
    const float u22 = t20*c0.z + t21*c1.z + t22*c2.z;

    // tcov = U * T3^T (symmetric part)
    const float tc00 = u00*t00 + u01*t01 + u02*t02;
    const float tc01 = u00*t10 + u01*t11 + u02*t12;
    const float tc02 = u00*t20 + u01*t21 + u02*t22;
    const float tc11 = u10*t10 + u11*t11 + u12*t12;
    const float tc12 = u10*t20 + u11*t21 + u12*t22;
    const float tc22 = u20*t20 + u21*t21 + u22*t22;

    const float a = d0.x + tc00;
    const float b = d0.y + tc01;
    const float c = d0.z + tc02;
    const float d = d1.y + tc11;
    const float e = d1.z + tc12;
    const float f = d2.z + tc22;

    const float A00 = d * f - e * e;
    const float A01 = c * e - b * f;
    const float A02 = b * e - c * d;
    const float A11 = a * f - c * c;
    const float A12 = b * c - a * e;
    const float A22 = a * d - b * b;

    const float det = a * A00 + b * A01 + c * A02;

    const float num = r0 * r0 * A00 + r1 * r1 * A11 + r2 * r2 * A22
                    + 2.0f * (r0 * r1 * A01 + r0 * r2 * A02 + r1 * r2 * A12);

    return num / det;
}

__global__ __launch_bounds__(BLOCK) void gicp_maha_kernel(
    const float* __restrict__ T,
    const f32x4* __restrict__ src,
    const f32x4* __restrict__ tar,
    const f32x4* __restrict__ cs,
    const f32x4* __restrict__ ct,
    const int*   __restrict__ idx,
    float*       __restrict__ partial,
    int n)
{
    const float t00 = T[0],  t01 = T[1],  t02 = T[2];
    const float t10 = T[4],  t11 = T[5],  t12 = T[6];
    const float t20 = T[8],  t21 = T[9],  t22 = T[10];
    const float t30 = T[12], t31 = T[13], t32 = T[14];

    const int stride = gridDim.x * BLOCK;   // grid exactly tiles n/UNROLL
    const int step   = stride * UNROLL;

    float local = 0.0f;
    for (int base = blockIdx.x * BLOCK + threadIdx.x; base < n; base += step) {
        if (base + 3 * stride < n) {
            float v0 = gicp_point(base,            t00,t01,t02,t10,t11,t12,t20,t21,t22,t30,t31,t32, src,tar,cs,ct,idx);
            float v1 = gicp_point(base +   stride, t00,t01,t02,t10,t11,t12,t20,t21,t22,t30,t31,t32, src,tar,cs,ct,idx);
            float v2 = gicp_point(base + 2*stride, t00,t01,t02,t10,t11,t12,t20,t21,t22,t30,t31,t32, src,tar,cs,ct,idx);
            float v3 = gicp_point(base + 3*stride, t00,t01,t02,t10,t11,t12,t20,t21,t22,t30,t31,t32, src,tar,cs,ct,idx);
            local += (v0 + v1) + (v2 + v3);
        } else {
            #pragma unroll
            for (int k = 0; k < UNROLL; ++k) {
                int i = base + k * stride;
                const float m = (i < n) ? 1.0f : 0.0f;
                i = (i < n) ? i : (n - 1);
                local += m * gicp_point(i, t00,t01,t02,t10,t11,t12,t20,t21,t22,t30,t31,t32, src,tar,cs,ct,idx);
            }
        }
    }

    // wave-64 reduction
    for (int off = 32; off > 0; off >>= 1)
        local += __shfl_down(local, off, 64);

    __shared__ float wsum[BLOCK / 64];
    const int wave = threadIdx.x >> 6;
    if ((threadIdx.x & 63) == 0) wsum[wave] = local;
    __syncthreads();
    if (threadIdx.x == 0) {
        float s = wsum[0];
        #pragma unroll
        for (int w = 1; w < BLOCK / 64; ++w) s += wsum[w];
        partial[blockIdx.x] = s;
    }
}

__global__ __launch_bounds__(256) void gicp_finalize_kernel(
    const float* __restrict__ partial, float* __restrict__ out,
    double scale, int nblocks)
{
    double s = 0.0;
    for (int k = threadIdx.x; k < nblocks; k += 256)
        s += (double)partial[k];
    for (int off = 32; off > 0; off >>= 1)
        s += __shfl_down(s, off, 64);
    __shared__ double wsum[4];
    const int wave = threadIdx.x >> 6;
    if ((threadIdx.x & 63) == 0) wsum[wave] = s;
    __syncthreads();
    if (threadIdx.x == 0)
        out[0] = (float)((wsum[0] + wsum[1] + wsum[2] + wsum[3]) * scale);
}

extern "C" void kernel_launch(void* const* d_in, const int* in_sizes, int n_in,
                              void* d_out, int out_size, void* d_ws, size_t ws_size,
                              hipStream_t stream) {
    const float* T   = (const float*)d_in[0];
    const f32x4* src = (const f32x4*)d_in[1];
    const f32x4* tar = (const f32x4*)d_in[2];
    const f32x4* cs  = (const f32x4*)d_in[3];
    const f32x4* ct  = (const f32x4*)d_in[4];
    const int*   idx = (const int*)d_in[5];
    const int n = in_sizes[1] / 4;          // src_points is (N,4) floats

    int nblocks = (n + BLOCK * UNROLL - 1) / (BLOCK * UNROLL);
    if (nblocks < 1) nblocks = 1;
    if (nblocks > MAX_BLOCKS) nblocks = MAX_BLOCKS;
    const int ws_cap = (int)(ws_size / sizeof(float));
    if (nblocks > ws_cap) nblocks = ws_cap;

    float* partial = (float*)d_ws;

    gicp_maha_kernel<<<nblocks, BLOCK, 0, stream>>>(T, src, tar, cs, ct, idx,
                                                    partial, n);
    gicp_finalize_kernel<<<1, 256, 0, stream>>>(partial, (float*)d_out,
                                                0.5 / (double)n, nblocks);
}